// Round 11
// baseline (212.754 us; speedup 1.0000x reference)
//
#include <hip/hip_runtime.h>
#include <hip/hip_bf16.h>
#include <cstdint>
#include <cstddef>

#define B_ 4
#define S_ 2048
#define D_ 1024
#define H_ 16
#define DK_ 64
#define NTOK (B_*S_)

typedef __bf16 bf16;
typedef __bf16 bf16x8 __attribute__((ext_vector_type(8)));
typedef short s16x4 __attribute__((ext_vector_type(4)));
typedef float f32x4 __attribute__((ext_vector_type(4)));

#define AS1 __attribute__((address_space(1)))
#define AS3 __attribute__((address_space(3)))

static __device__ __forceinline__ short f2bf_s(float f) {
    return __builtin_bit_cast(short, (__bf16)f);
}

static __device__ __forceinline__ f32x4 mfma16(s16x4 a, s16x4 b, f32x4 c) {
#if __has_builtin(__builtin_amdgcn_mfma_f32_16x16x16bf16_1k)
    return __builtin_amdgcn_mfma_f32_16x16x16bf16_1k(a, b, c, 0, 0, 0);
#else
    asm volatile("v_mfma_f32_16x16x16_bf16 %0, %1, %2, %0\n\ts_nop 7\n\ts_nop 7"
                 : "+v"(c) : "v"(a), "v"(b));
    return c;
#endif
}

// ---------------- fused fp32 -> bf16 convert: [X | Wq | Wk | Wv | Wo] ----------------
__global__ void cvt_all(const float* __restrict__ x, const float* __restrict__ wq,
                        const float* __restrict__ wk, const float* __restrict__ wv,
                        const float* __restrict__ wo, bf16* __restrict__ dst) {
    const int NX8 = NTOK * D_ / 8;
    const int W8 = D_ * D_ / 8;          // 131072 = 2^17
    int i = blockIdx.x * blockDim.x + threadIdx.x;
    if (i >= NX8 + 4 * W8) return;
    const float* src; int j;
    if (i < NX8) { src = x; j = i; }
    else {
        int k = i - NX8;
        int w = k >> 17;
        j = k & (W8 - 1);
        src = w == 0 ? wq : (w == 1 ? wk : (w == 2 ? wv : wo));
    }
    const float4* s4 = reinterpret_cast<const float4*>(src) + (size_t)j * 2;
    float4 a = s4[0], b = s4[1];
    bf16x8 o;
    o[0] = (bf16)a.x; o[1] = (bf16)a.y; o[2] = (bf16)a.z; o[3] = (bf16)a.w;
    o[4] = (bf16)b.x; o[5] = (bf16)b.y; o[6] = (bf16)b.z; o[7] = (bf16)b.w;
    reinterpret_cast<bf16x8*>(dst)[i] = o;
}

// ---------------- RoPE cos/sin table: [NTOK][32] float2 ----------------
__global__ void rope_table(const int* __restrict__ pos, float2* __restrict__ tab) {
    int i = blockIdx.x * blockDim.x + threadIdx.x;
    if (i >= NTOK * 32) return;
    int n = i >> 5, p = i & 31;
    float pf = (float)pos[n];
    float freq = powf(10000.0f, -(float)p * (1.0f / 32.0f));
    float ang = pf * freq;
    float s, c;
    sincosf(ang, &s, &c);
    tab[i] = make_float2(c, s);
}

// ---------------- 128x128 GEMM, BK=64, counted-vmcnt (unchanged from R10) ----------------
template<int MODE>
__global__ __launch_bounds__(256, 2)
void gemm128(const bf16* __restrict__ A, const bf16* __restrict__ Bw,
             void* __restrict__ OutP, const float2* __restrict__ tab) {
    const float SCL2E = 0.125f * 1.44269504088896340736f;
    constexpr int NKT = 16;                       // K/64
    __shared__ alignas(16) bf16 lds[2][(128 + 128) * 64];
    const int tid = threadIdx.x;
    const int lane = tid & 63;
    const int wid = tid >> 6;
    const int wm = wid >> 1;                      // 0..1
    const int wn = wid & 1;                       // 0..1
    const int lr = lane & 15, lg = lane >> 4;
    const int m0 = blockIdx.x * 128;
    const int n0g = blockIdx.y * 128;             // spans 3072 for QKV

    f32x4 acc[4][4] = {};

    auto stage = [&](int kt, int bufi) {
        bf16* dst = &lds[bufi][0];
#pragma unroll
        for (int j = 0; j < 4; ++j) {
            int flat = j * 256 + tid;
            int r = flat >> 3, c = flat & 7;
            const bf16* src = A + (size_t)(m0 + r) * 1024 + kt * 64 + ((c ^ (r & 7)) << 3);
            __builtin_amdgcn_global_load_lds((const AS1 uint32_t*)src,
                                             (AS3 uint32_t*)(dst + (size_t)flat * 8), 16, 0, 0);
        }
#pragma unroll
        for (int j = 0; j < 4; ++j) {
            int flat = j * 256 + tid;
            int r = flat >> 3, c = flat & 7;
            const bf16* src = Bw + (size_t)(n0g + r) * 1024 + kt * 64 + ((c ^ (r & 7)) << 3);
            __builtin_amdgcn_global_load_lds((const AS1 uint32_t*)src,
                                             (AS3 uint32_t*)(dst + 128 * 64 + (size_t)flat * 8), 16, 0, 0);
        }
    };

    stage(0, 0);

    for (int kt = 0; kt < NKT; ++kt) {
        const bf16* bufA = &lds[kt & 1][0];
        const bf16* bufB = bufA + 128 * 64;

        asm volatile("" ::: "memory");
        __builtin_amdgcn_s_barrier();             // BAR-A
        asm volatile("" ::: "memory");
        if (kt + 1 < NKT) {
            stage(kt + 1, (kt + 1) & 1);
            asm volatile("s_waitcnt vmcnt(8)" ::: "memory");
        } else {
            asm volatile("s_waitcnt vmcnt(0)" ::: "memory");
        }
        __builtin_amdgcn_s_barrier();             // BAR-B
        asm volatile("" ::: "memory");

        const int sx = lr & 7;
        bf16x8 af[4][2], bfr[4][2];
#pragma unroll
        for (int mf = 0; mf < 4; ++mf)
#pragma unroll
            for (int kh = 0; kh < 2; ++kh)
                af[mf][kh] = *reinterpret_cast<const bf16x8*>(
                    &bufA[(wm * 64 + mf * 16 + lr) * 64 + (((kh * 4 + lg) ^ sx) << 3)]);
#pragma unroll
        for (int nf = 0; nf < 4; ++nf)
#pragma unroll
            for (int kh = 0; kh < 2; ++kh)
                bfr[nf][kh] = *reinterpret_cast<const bf16x8*>(
                    &bufB[(wn * 64 + nf * 16 + lr) * 64 + (((kh * 4 + lg) ^ sx) << 3)]);
        __builtin_amdgcn_s_setprio(1);
#pragma unroll
        for (int mf = 0; mf < 4; ++mf)
#pragma unroll
            for (int nf = 0; nf < 4; ++nf)
#pragma unroll
                for (int kh = 0; kh < 2; ++kh)
                    acc[mf][nf] = __builtin_amdgcn_mfma_f32_16x16x32_bf16(af[mf][kh], bfr[nf][kh], acc[mf][nf], 0, 0, 0);
        __builtin_amdgcn_s_setprio(0);
    }

#pragma unroll
    for (int mf = 0; mf < 4; ++mf) {
#pragma unroll
        for (int nf = 0; nf < 4; ++nf) {
#pragma unroll
            for (int r = 0; r < 4; ++r) {
                int row = m0 + wm * 64 + mf * 16 + lg * 4 + r;
                int colg = n0g + wn * 64 + nf * 16 + lr;
                float v = acc[mf][nf][r];
                if (MODE == 2) {
                    ((float*)OutP)[(size_t)row * 1024 + colg] = v;
                } else {
                    int which = colg >> 10;          // block-uniform
                    int col = colg & 1023;
                    bf16* O = (bf16*)OutP + (size_t)which * NTOK * D_;
                    if (which < 2) {
                        float partner = __shfl_xor(v, 1, 64);
                        float2 cs = tab[(size_t)row * 32 + ((col >> 1) & 31)];
                        float o = (col & 1) ? fmaf(v, cs.x, partner * cs.y)
                                            : fmaf(v, cs.x, -partner * cs.y);
                        if (which == 0) o *= SCL2E;
                        O[(size_t)row * D_ + col] = (bf16)o;
                    } else {
                        O[(size_t)row * D_ + col] = (bf16)v;
                    }
                }
            }
        }
    }
}

// ---------------- causal flash attention: 64-row paired strips, grid (16,64) ----------------
// Block = strips sA=bx, sB=31-bx (64 q-rows each; wave owns 16 rows/strip).
// Per-block compute constant (34 tile-units); heavy blocks (bx=0) dispatch first.
// 1024 blocks = 4/CU -> 16 waves/CU for cross-wave MFMA/VALU overlap (R10 lesson:
// occupancy was grid-capped at 512 blocks, not resource-capped).
// Per-tile math = R6-verified code with the qs loop collapsed. No launch_bounds
// min-waves (R7/R8 lesson).
__global__ __launch_bounds__(256, 2)
void flash_attn8(const bf16* __restrict__ Q, const bf16* __restrict__ Kr,
                 const bf16* __restrict__ V, bf16* __restrict__ O) {
    __shared__ bf16 Ks[2][64 * 64];
    __shared__ bf16 Vt[2][64 * 64];
    const int tid = threadIdx.x, lane = tid & 63, w = tid >> 6;
    const int lr = lane & 15, lg = lane >> 4;
    const int bx = blockIdx.x;                    // 0..15
    const int sA = bx, sB = 31 - bx;
    const int q0[2] = { sA * 64, sB * 64 };
    const int ntS[2] = { sA + 1, sB + 1 };
    const int NT = ntS[1];
    const int bh = blockIdx.y;
    const int b = bh >> 4, h = bh & 15;
    const size_t base = ((size_t)b * S_) * D_ + (size_t)h * DK_;

    // Q fragments (B operand of swapped QK): col=lane&15=q, k=lg*8 (+32)
    bf16x8 aq[2][2];
#pragma unroll
    for (int si = 0; si < 2; ++si) {
        int qrow = q0[si] + w * 16 + lr;
        const bf16* qp = Q + base + (size_t)qrow * D_ + lg * 8;
        aq[si][0] = *reinterpret_cast<const bf16x8*>(qp);
        aq[si][1] = *reinterpret_cast<const bf16x8*>(qp + 32);
    }

    f32x4 acc[2][4] = {};
    float m_run[2] = {-1e30f, -1e30f};
    float l_run[2] = {0.f, 0.f};

    const int sjj = tid >> 3;
    const int se0 = (tid & 7) * 8;
    const int vx = tid & 7;
    bf16x8 kreg[2], vreg[2];
#pragma unroll
    for (int i = 0; i < 2; ++i) {
        int row = sjj + i * 32;
        kreg[i] = *reinterpret_cast<const bf16x8*>(&Kr[base + (size_t)row * D_ + se0]);
        vreg[i] = *reinterpret_cast<const bf16x8*>(&V [base + (size_t)row * D_ + se0]);
    }

    for (int t = 0; t < NT; ++t) {
        const int j0 = t * 64;
        bf16* KsB = Ks[t & 1];
        bf16* VtB = Vt[t & 1];
#pragma unroll
        for (int i = 0; i < 2; ++i) {
            int jj = sjj + i * 32;
            *reinterpret_cast<bf16x8*>(&KsB[jj * 64 + (se0 ^ ((jj & 7) << 3))]) = kreg[i];
#pragma unroll
            for (int q = 0; q < 8; ++q) {
                int dd = se0 + q;
                int vswz = ((q ^ vx) & 7) << 3;
                VtB[dd * 64 + (jj ^ vswz)] = vreg[i][q];
            }
        }
        if (t + 1 < NT) {
#pragma unroll
            for (int i = 0; i < 2; ++i) {
                int row = (t + 1) * 64 + sjj + i * 32;
                kreg[i] = *reinterpret_cast<const bf16x8*>(&Kr[base + (size_t)row * D_ + se0]);
                vreg[i] = *reinterpret_cast<const bf16x8*>(&V [base + (size_t)row * D_ + se0]);
            }
        }
        __syncthreads();

#pragma unroll
        for (int si = 0; si < 2; ++si) {
            if (t >= ntS[si]) continue;                      // strip A finished (block-uniform)
            const int qrow0 = q0[si] + w * 16;
            if (j0 > qrow0 + 15) continue;                   // fully masked for this wave

            // S^T = K Q^T (Q pre-scaled by 0.125*log2e)
            f32x4 sc[4];
            __builtin_amdgcn_s_setprio(1);
#pragma unroll
            for (int nt = 0; nt < 4; ++nt) {
                int krow = nt * 16 + lr;
                int swz = (krow & 7) << 3;
                bf16x8 a0 = *reinterpret_cast<const bf16x8*>(&KsB[krow * 64 + ((lg * 8) ^ swz)]);
                bf16x8 a1 = *reinterpret_cast<const bf16x8*>(&KsB[krow * 64 + ((32 + lg * 8) ^ swz)]);
                f32x4 tv = {};
                tv = __builtin_amdgcn_mfma_f32_16x16x32_bf16(a0, aq[si][0], tv, 0, 0, 0);
                tv = __builtin_amdgcn_mfma_f32_16x16x32_bf16(a1, aq[si][1], tv, 0, 0, 0);
                sc[nt] = tv;
            }
            __builtin_amdgcn_s_setprio(0);

            const int qrow = qrow0 + lr;                     // this lane's q-row
            if (j0 + 63 > qrow0) {                           // diagonal tile: mask
#pragma unroll
                for (int nt = 0; nt < 4; ++nt)
#pragma unroll
                    for (int r = 0; r < 4; ++r) {
                        int kv = j0 + nt * 16 + lg * 4 + r;
                        if (kv > qrow) sc[nt][r] = -1e30f;
                    }
            }
            float tmax = sc[0][0];
#pragma unroll
            for (int nt = 0; nt < 4; ++nt)
#pragma unroll
                for (int r = 0; r < 4; ++r) tmax = fmaxf(tmax, sc[nt][r]);
            tmax = fmaxf(tmax, __shfl_xor(tmax, 16, 64));
            tmax = fmaxf(tmax, __shfl_xor(tmax, 32, 64));
            float mold = m_run[si];
            if (!__all(tmax - mold <= 8.0f)) {
                float mnew = fmaxf(mold, tmax);
                float corr = exp2f(mold - mnew);
                m_run[si] = mnew;
                l_run[si] *= corr;
#pragma unroll
                for (int r = 0; r < 4; ++r) {
                    float cr = __shfl(corr, (lane & 48) | (lg * 4 + r), 64);
#pragma unroll
                    for (int dt = 0; dt < 4; ++dt) acc[si][dt][r] *= cr;
                }
            }
            float mnow = m_run[si];
            s16x4 ap[4];
            float rs = 0.f;
#pragma unroll
            for (int nt = 0; nt < 4; ++nt)
#pragma unroll
                for (int r = 0; r < 4; ++r) {
                    float p = exp2f(sc[nt][r] - mnow);
                    rs += p;
                    ap[nt][r] = f2bf_s(p);
                }
            rs += __shfl_xor(rs, 16, 64);
            rs += __shfl_xor(rs, 32, 64);
            l_run[si] += rs;

            // PV: A = P (in-register), B = V^T slices
            __builtin_amdgcn_s_setprio(1);
#pragma unroll
            for (int dt = 0; dt < 4; ++dt) {
                int vrow = dt * 16 + lr;
                int vswz = (((vrow & 7) ^ (vrow >> 3)) & 7) << 3;
                s16x4 bv[4];
#pragma unroll
                for (int nt = 0; nt < 4; ++nt)
                    bv[nt] = *reinterpret_cast<const s16x4*>(&VtB[vrow * 64 + ((nt * 16 + lg * 4) ^ vswz)]);
#pragma unroll
                for (int nt = 0; nt < 4; ++nt)
                    acc[si][dt] = mfma16(ap[nt], bv[nt], acc[si][dt]);
            }
            __builtin_amdgcn_s_setprio(0);
        }
    }

    // epilogue (both strips always valid: sA=0..15, sB=31..16)
#pragma unroll
    for (int si = 0; si < 2; ++si) {
        float inv = __builtin_amdgcn_rcpf(l_run[si]);
#pragma unroll
        for (int r = 0; r < 4; ++r) {
            float invr = __shfl(inv, (lane & 48) | (lg * 4 + r), 64);
            int row = q0[si] + w * 16 + lg * 4 + r;
#pragma unroll
            for (int dt = 0; dt < 4; ++dt)
                O[base + (size_t)row * D_ + dt * 16 + lr] = (bf16)(acc[si][dt][r] * invr);
        }
    }
}

// ---------------- launcher ----------------
extern "C" void kernel_launch(void* const* d_in, const int* in_sizes, int n_in,
                              void* d_out, int out_size, void* d_ws, size_t ws_size,
                              hipStream_t stream) {
    const float* x  = (const float*)d_in[0];
    const int*   tp = (const int*)d_in[1];
    const float* wq = (const float*)d_in[2];
    const float* wk = (const float*)d_in[3];
    const float* wv = (const float*)d_in[4];
    const float* wo = (const float*)d_in[5];

    bf16* ws = (bf16*)d_ws;
    bf16* Xbf = ws;
    bf16* Wqb = Xbf + (size_t)NTOK * D_;          // [3072][1024] packed Wq|Wk|Wv
    bf16* Wkb = Wqb + (size_t)D_ * D_;
    bf16* Wvb = Wkb + (size_t)D_ * D_;
    bf16* Wob = Wvb + (size_t)D_ * D_;
    bf16* Qr  = Wob + (size_t)D_ * D_;
    bf16* Kb  = Qr + (size_t)NTOK * D_;
    bf16* Vb  = Kb + (size_t)NTOK * D_;
    bf16* AO  = Vb + (size_t)NTOK * D_;
    float2* tab = (float2*)(AO + (size_t)NTOK * D_);
    (void)ws_size; (void)in_sizes; (void)n_in; (void)out_size;
    (void)Wkb; (void)Wvb;

    {
        int ntot8 = (NTOK * D_ + 4 * D_ * D_) / 8;
        cvt_all<<<(ntot8 + 255) / 256, 256, 0, stream>>>(x, wq, wk, wv, wo, Xbf);
    }
    rope_table<<<(NTOK * 32 + 255) / 256, 256, 0, stream>>>(tp, tab);

    // QKV: one GEMM vs packed [3072][1024] weights; grid 64x24 = 1536 blocks
    gemm128<1><<<dim3(NTOK / 128, 24), 256, 0, stream>>>(Xbf, Wqb, Qr, tab);

    flash_attn8<<<dim3(16, B_ * H_), 256, 0, stream>>>(Qr, Kb, Vb, AO);

    // out-projection: grid 64x8 = 512 blocks, fp32 out
    gemm128<2><<<dim3(NTOK / 128, D_ / 128), 256, 0, stream>>>(AO, Wob, d_out, nullptr);
}